// Round 7
// baseline (571.412 us; speedup 1.0000x reference)
//
#include <hip/hip_runtime.h>
#include <cfloat>

// VQ forward, MI355X. z[16,256,32,32] f32, emb[8192,256] f32, proj[256,256] f32.
// N = 16384 rows, K = 8192 codes, D = 256.
// d_out (floats): out[4194304] | loss | commitment | codebook_loss | idx_as_float[16384]
//
// R8 three-phase argmin:
//  scanA (bf16 MFMA): per-row global approx-min (atomicMin u32 monof).
//  k_thresh: thr[n] = min + DLT, DLT=1e-3 >> worst-case score error 3.2e-4.
//  scanC (bit-identical computation): emit k with sc <= thr[n] into per-row slots.
//  k_rescore: exact fp32 rescore of slots; packed (monof<<32|k) min -> first-index ties.
//
// R15: back to the VERIFIED R12 dataflow (no LDS, no barriers-with-async, no inline
//  asm fences — R13/R14's hand pipeline raced twice and is abandoned), with R12's
//  measured defect fixed: WRITE_SIZE 4.5->10.5 MB revealed register SPILLS
//  (live set ~180 > 128 reported). Changes vs R12:
//   - each kt's 8 col-tiles split into two quads (cq=0,1): acc[2][4]=32 regs,
//     B bufs 2x4=32, A bufs 2x2=16 -> core ~80 live, total ~115 -> no spills and
//     __launch_bounds__(256,4): 4 waves/SIMD (4 blocks/CU) for latency hiding.
//   - per-acc-element MFMA chain still d32-ascending -> scores BIT-IDENTICAL to
//     R12/R8 chain (ct chunking does not reorder any element's accumulation).
//   - one plain __syncthreads() per kt: bounds wave drift so partner waves
//     (rowhalf pair: same B; colhalf pair: same A) hit L1 on the duplicate reads.
//   - sentinel guards in k_rescore/k_output retained (wrong-answer, not fault).

constexpr int Dd = 256;
constexpr float INV_M = 1.0f / 4194304.0f;
constexpr float DLT = 1e-3f;

typedef unsigned short u16;
typedef unsigned int u32;
typedef __attribute__((ext_vector_type(8))) short short8;   // 8 bf16
typedef __attribute__((ext_vector_type(4))) float f32x4;

__device__ __forceinline__ unsigned monof(float f) {
  unsigned u = __float_as_uint(f);
  return (u & 0x80000000u) ? ~u : (u | 0x80000000u);
}
__device__ __forceinline__ float unmonof(unsigned p) {
  unsigned u = (p & 0x80000000u) ? (p & 0x7FFFFFFFu) : ~p;
  return __uint_as_float(u);
}
__device__ __forceinline__ u16 f2bf(float x) {   // RNE float->bf16 bits
  unsigned u = __float_as_uint(x);
  u += 0x7FFFu + ((u >> 16) & 1u);
  return (u16)(u >> 16);
}

// ---- K1: codebook = emb @ proj^T -> cb[k][d] fp32 + ef bf16 fragment-order ----
__global__ __launch_bounds__(256)
void k_codebook(const float* __restrict__ emb, const float* __restrict__ proj,
                float* __restrict__ cb, u16* __restrict__ ef) {
  __shared__ float et[64 * 65];
  __shared__ float pt[64 * 65];
  __shared__ __align__(16) u16 tileT[64 * 72];
  const int t = threadIdx.x;
  const int tx = t & 15, ty = t >> 4;
  const int kb = blockIdx.x * 64;
  const int db = blockIdx.y * 64;
  float acc[4][4];
#pragma unroll
  for (int u = 0; u < 4; ++u)
#pragma unroll
    for (int v = 0; v < 4; ++v) acc[u][v] = 0.f;

  const int jm = t & 15;
  const int q  = t >> 4;

  for (int jc = 0; jc < Dd; jc += 64) {
    __syncthreads();
#pragma unroll
    for (int i = 0; i < 4; ++i) {
      const int row = q + i * 16;
      const float4 e4 = *(const float4*)(emb  + (size_t)(kb + row) * Dd + jc + jm * 4);
      const float4 p4 = *(const float4*)(proj + (size_t)(db + row) * Dd + jc + jm * 4);
      et[(jm*4 + 0) * 65 + row] = e4.x;
      et[(jm*4 + 1) * 65 + row] = e4.y;
      et[(jm*4 + 2) * 65 + row] = e4.z;
      et[(jm*4 + 3) * 65 + row] = e4.w;
      pt[(jm*4 + 0) * 65 + row] = p4.x;
      pt[(jm*4 + 1) * 65 + row] = p4.y;
      pt[(jm*4 + 2) * 65 + row] = p4.z;
      pt[(jm*4 + 3) * 65 + row] = p4.w;
    }
    __syncthreads();
#pragma unroll 16
    for (int j = 0; j < 64; ++j) {
      float a[4], b[4];
#pragma unroll
      for (int u = 0; u < 4; ++u) a[u] = et[j*65 + ty*4 + u];
#pragma unroll
      for (int v = 0; v < 4; ++v) b[v] = pt[j*65 + tx*4 + v];
#pragma unroll
      for (int u = 0; u < 4; ++u)
#pragma unroll
        for (int v = 0; v < 4; ++v) acc[u][v] = fmaf(a[u], b[v], acc[u][v]);
    }
  }
  // fp32 cb (linear) + bf16 tile to LDS for fragment-order shuffle
#pragma unroll
  for (int u = 0; u < 4; ++u) {
    const int k = kb + ty*4 + u;
#pragma unroll
    for (int v = 0; v < 4; ++v) {
      const int d = db + tx*4 + v;
      const float val = acc[u][v];
      cb[(size_t)k * Dd + d] = val;
      tileT[(ty*4 + u) * 72 + tx*4 + v] = f2bf(val);
    }
  }
  __syncthreads();
  // emit 512 fragment granules (16 B each), coalesced
  uint4* ef16 = (uint4*)ef;
#pragma unroll
  for (int w2 = 0; w2 < 2; ++w2) {
    const int uu = w2 * 256 + t;
    const int k16g = uu >> 7;            // 0..3 (16-k group within tile)
    const int d32g = (uu >> 6) & 1;      // 0..1 (32-d group within tile)
    const int ln   = uu & 63;            // fragment lane
    const int klo  = k16g * 16 + (ln & 15);
    const int dlo  = d32g * 32 + (ln >> 4) * 8;
    ef16[((kb >> 4) + k16g) * 512 + ((db >> 5) + d32g) * 64 + ln] =
        *(const uint4*)&tileT[klo * 72 + dlo];
  }
}

// ---- K1b: per-code norms (ascending-d fmaf chain) ----
__global__ __launch_bounds__(256)
void k_norms(const float* __restrict__ cb, float* __restrict__ norms) {
  const int k = blockIdx.x * 256 + threadIdx.x;
  const float* row = cb + (size_t)k * Dd;
  float s = 0.f;
  for (int d = 0; d < Dd; d += 4) {
    const float4 v = *(const float4*)(row + d);
    s = fmaf(v.x, v.x, s);
    s = fmaf(v.y, v.y, s);
    s = fmaf(v.z, v.z, s);
    s = fmaf(v.w, v.w, s);
  }
  norms[k] = s;
}

// ---- K1c: transpose z -> zf bf16 fragment-order + znorm ----
__global__ __launch_bounds__(256)
void k_prep_z(const float* __restrict__ z, u16* __restrict__ zf,
              float* __restrict__ znorm) {
  __shared__ float tile[256 * 33];
  const int t = threadIdx.x;
  const int blk = blockIdx.x;            // b*32 + h
  const int w = t & 31, rg = t >> 5;
  const size_t zbase = (size_t)(blk >> 5) * 262144 + (size_t)(blk & 31) * 32 + w;
#pragma unroll 8
  for (int i = 0; i < 32; ++i) {
    const int d = rg * 32 + i;
    tile[d * 33 + w] = z[zbase + (size_t)d * 1024];
  }
  __syncthreads();
  if (t < 32) {
    float s = 0.f;
    for (int d = 0; d < Dd; ++d) {
      const float v = tile[d * 33 + t];
      s = fmaf(v, v, s);
    }
    znorm[blk * 32 + t] = s;
  }
  // fragment-order write: granule U = ((n>>4)*8 + d32)*64 + qd*16 + (n&15)
  const int ml16 = t & 15;
  const int seg  = (t >> 4) & 7;         // d32 group
  const int hi   = t >> 7;               // n16 group within block (0/1)
  const int nl   = hi * 16 + ml16;       // row 0..31 within block
  uint4* zf16 = (uint4*)zf;
  const int ubase = ((blk * 2 + hi) * 8 + seg) * 64 + ml16;
#pragma unroll
  for (int j = 0; j < 4; ++j) {          // qd octet
    u16 hb[8];
#pragma unroll
    for (int e = 0; e < 8; ++e)
      hb[e] = f2bf(tile[(seg * 32 + j * 8 + e) * 33 + nl]);
    zf16[ubase + j * 16] = *(const uint4*)hb;
  }
}

// ---- K2: MFMA scan, register streaming (R12 dataflow), spill-free geometry ----
// Block 64 rows x 1024 cols; wave (rowhalf, colhalf) = 32 rows x 128 cols.
// Per kt: two col-quads (cq), each 4 ct tiles; acc[2][4]; A/B double-buffered
// per d32 step (distance-1). No LDS; one plain __syncthreads per kt to bound
// wave drift so partner waves hit L1 on duplicate A/B granules.
template <bool EMIT>
__global__ __launch_bounds__(256, 4)
void k_scan(const u16* __restrict__ zf, const u16* __restrict__ ef,
            const float* __restrict__ norms, const float* __restrict__ znorm,
            u32* __restrict__ rowminG, const float* __restrict__ rowThr,
            u32* __restrict__ rowcnt, u16* __restrict__ slots) {
  const int t    = threadIdx.x;
  const int lane = t & 63;
  const int ml   = lane & 15;
  const int qd   = lane >> 4;
  const int wvu  = __builtin_amdgcn_readfirstlane(t >> 6);
  const int rowhalf = wvu & 1;           // 0/1 -> 32 rows
  const int colhalf = wvu >> 1;          // 0/1 -> 128 cols (of kt's 256)
  const int bid  = blockIdx.x;
  const int kb   = (bid & 7) * 1024;     // colgroup -> XCD-local ef reuse
  const int nb   = (bid >> 3) * 64;

  const uint4* zf16 = (const uint4*)zf;
  const uint4* ef16 = (const uint4*)ef;
  // A granule (rt,d32): za + rt*512 + d32*64
  const uint4* za = zf16 + (size_t)((nb >> 4) + rowhalf * 2) * 512 + lane;
  // B granule (kt,cq,ct,d32): eb + ((kt*16)+(cq*4)+ct)*512 + d32*64
  const uint4* eb = ef16 + (size_t)((kb >> 4) + colhalf * 8) * 512 + lane;

  // per-thread rows: n = nb + rowhalf*32 + rt*16 + qd*4 + r
  float zn[2][4], thr[2][4];
#pragma unroll
  for (int rt = 0; rt < 2; ++rt) {
    const int nr = nb + rowhalf * 32 + rt * 16 + qd * 4;
    const f32x4 z4 = *(const f32x4*)(znorm + nr);
#pragma unroll
    for (int r = 0; r < 4; ++r) zn[rt][r] = z4[r];
    if (EMIT) {
      const f32x4 t4 = *(const f32x4*)(rowThr + nr);
#pragma unroll
      for (int r = 0; r < 4; ++r) thr[rt][r] = t4[r];
    }
  }

  float mv[2][4];
#pragma unroll
  for (int rt = 0; rt < 2; ++rt)
#pragma unroll
    for (int r = 0; r < 4; ++r) mv[rt][r] = FLT_MAX;

#pragma unroll 1
  for (int kt = 0; kt < 4; ++kt) {
    const size_t ekt = (size_t)kt * 16 * 512;
#pragma unroll
    for (int cq = 0; cq < 2; ++cq) {
      const uint4* ecq = eb + ekt + (size_t)(cq * 4) * 512;

      f32x4 acc[2][4];
#pragma unroll
      for (int rt = 0; rt < 2; ++rt)
#pragma unroll
        for (int ct = 0; ct < 4; ++ct) acc[rt][ct] = (f32x4)0.f;

      short8 Aa0[2], Aa1[2], Bb0[4], Bb1[4];
      // prologue: d32 = 0 into buf0
#pragma unroll
      for (int rt = 0; rt < 2; ++rt) Aa0[rt] = *(const short8*)(za + rt * 512);
#pragma unroll
      for (int ct = 0; ct < 4; ++ct) Bb0[ct] = *(const short8*)(ecq + ct * 512);

#pragma unroll
      for (int d32 = 0; d32 < 8; ++d32) {
        if (d32 < 7) {                       // distance-1 prefetch of d32+1
          const int off = (d32 + 1) * 64;
          if (d32 & 1) {                     // current buf1 -> fill buf0
#pragma unroll
            for (int rt = 0; rt < 2; ++rt)
              Aa0[rt] = *(const short8*)(za + rt * 512 + off);
#pragma unroll
            for (int ct = 0; ct < 4; ++ct)
              Bb0[ct] = *(const short8*)(ecq + ct * 512 + off);
          } else {                           // current buf0 -> fill buf1
#pragma unroll
            for (int rt = 0; rt < 2; ++rt)
              Aa1[rt] = *(const short8*)(za + rt * 512 + off);
#pragma unroll
            for (int ct = 0; ct < 4; ++ct)
              Bb1[ct] = *(const short8*)(ecq + ct * 512 + off);
          }
        }
        if (d32 & 1) {
#pragma unroll
          for (int ct = 0; ct < 4; ++ct)
#pragma unroll
            for (int rt = 0; rt < 2; ++rt)
              acc[rt][ct] = __builtin_amdgcn_mfma_f32_16x16x32_bf16(
                  Aa1[rt], Bb1[ct], acc[rt][ct], 0, 0, 0);
        } else {
#pragma unroll
          for (int ct = 0; ct < 4; ++ct)
#pragma unroll
            for (int rt = 0; rt < 2; ++rt)
              acc[rt][ct] = __builtin_amdgcn_mfma_f32_16x16x32_bf16(
                  Aa0[rt], Bb0[ct], acc[rt][ct], 0, 0, 0);
        }
      }

      // fold this (kt,cq)'s 64 cols (per thread: 4 cols via ct, rows via rt,r)
#pragma unroll
      for (int ct = 0; ct < 4; ++ct) {
        const int k = kb + kt * 256 + colhalf * 128 + cq * 64 + ct * 16 + ml;
        const float nkv = norms[k];
#pragma unroll
        for (int rt = 0; rt < 2; ++rt)
#pragma unroll
          for (int r = 0; r < 4; ++r) {
            const float sc = (zn[rt][r] + nkv) - 2.0f * acc[rt][ct][r];
            if (!EMIT) {
              mv[rt][r] = fminf(mv[rt][r], sc);
            } else if (sc <= thr[rt][r]) {
              const int n = nb + rowhalf * 32 + rt * 16 + qd * 4 + r;
              const u32 pos = atomicAdd(&rowcnt[n], 1u);
              if (pos < 32u) slots[n * 32 + pos] = (u16)k;
            }
          }
      }
    }
    __syncthreads();   // plain barrier (no async staging): bounds wave drift
  }                    // so partner waves' duplicate A/B reads hit L1

  if (!EMIT) {
#pragma unroll
    for (int rt = 0; rt < 2; ++rt)
#pragma unroll
      for (int r = 0; r < 4; ++r) {
        float m = mv[rt][r];
#pragma unroll
        for (int s = 1; s < 16; s <<= 1) m = fminf(m, __shfl_xor(m, s, 64));
        if (ml == 0)
          atomicMin(&rowminG[nb + rowhalf * 32 + rt * 16 + qd * 4 + r], monof(m));
      }
  }
}

// ---- K2b: threshold ----
__global__ __launch_bounds__(256)
void k_thresh(const u32* __restrict__ rowminG, float* __restrict__ rowThr) {
  const int n = blockIdx.x * 256 + threadIdx.x;
  rowThr[n] = unmonof(rowminG[n]) + DLT;
}

// ---- K2c: exact rescore of slot candidates ----
// Block per (b,h): 32 rows; LDS z-tile [32][261] fp32; wave per 8 rows.
__global__ __launch_bounds__(256)
void k_rescore(const float* __restrict__ z, const float* __restrict__ cb,
               const float* __restrict__ norms, const float* __restrict__ znorm,
               const u32* __restrict__ rowcnt, const u16* __restrict__ slots,
               unsigned long long* __restrict__ packed) {
  __shared__ float ztl[32 * 261];
  const int t = threadIdx.x;
  const int blk = blockIdx.x;          // b*32 + h
  const int w = t & 31, dg = t >> 5;
  const size_t zbase = (size_t)(blk >> 5) * 262144 + (size_t)(blk & 31) * 32;
#pragma unroll 8
  for (int i = 0; i < 32; ++i) {
    const int d = dg * 32 + i;
    ztl[w * 261 + d] = z[zbase + (size_t)d * 1024 + w];
  }
  __syncthreads();

  const int lane = t & 63;
  const int wv = t >> 6;               // 4 waves
  // 4 waves x 8 rows each
#pragma unroll 1
  for (int i = 0; i < 8; ++i) {
    const int rl = wv * 8 + i;
    const int n = blk * 32 + rl;
    const u32 cnt = min(rowcnt[n], 32u);
    const float znr = znorm[n];
    unsigned long long best = 0xFFFFFFFFFFFFFFFFull;
    for (u32 c = 0; c < cnt; ++c) {
      const int k = (int)slots[n * 32 + c] & 8191;   // guard: in-bounds gather
      const float4 c4 = *(const float4*)(cb + (size_t)k * Dd + lane * 4);
      const float* zp = ztl + rl * 261 + lane * 4;
      float p = 0.f;
      p = fmaf(zp[0], c4.x, p);
      p = fmaf(zp[1], c4.y, p);
      p = fmaf(zp[2], c4.z, p);
      p = fmaf(zp[3], c4.w, p);
#pragma unroll
      for (int s = 1; s < 64; s <<= 1) p += __shfl_xor(p, s, 64);
      const float sc = (znr + norms[k]) - 2.0f * p;   // quantized fold
      const unsigned long long pk =
          ((unsigned long long)monof(sc) << 32) | (unsigned)k;
      if (pk < best) best = pk;                        // lexicographic: ties -> min k
    }
    if (lane == 0 && cnt > 0) packed[n] = best;
  }
}

// ---- K3: gather codes, write out (NCHW), idx floats, reduce SSE ----
__global__ __launch_bounds__(256)
void k_output(const float* __restrict__ z, const float* __restrict__ cb,
              const unsigned long long* __restrict__ packed,
              float* __restrict__ out, float* __restrict__ idxf,
              float* __restrict__ ssum) {
  __shared__ float zqT[256 * 33];
  __shared__ float part[4];
  const int t = threadIdx.x;
  const int blk = blockIdx.x;       // = b*32 + h
  const int nbase = blk * 32;

  {
    const int nl = t >> 3, m = t & 7;
    // guard the GATHER address only (&8191): if upstream ever leaves the
    // sentinel, we return wrong values (checker catches) instead of faulting.
    const int idx = (int)(packed[nbase + nl] & 0xFFFFFFFFull) & 8191;
    const float* row = cb + (size_t)idx * Dd;
#pragma unroll
    for (int i = 0; i < 8; ++i) {
      const int d0 = m * 4 + i * 32;
      const float4 v = *(const float4*)(row + d0);
      zqT[(d0 + 0) * 33 + nl] = v.x;
      zqT[(d0 + 1) * 33 + nl] = v.y;
      zqT[(d0 + 2) * 33 + nl] = v.z;
      zqT[(d0 + 3) * 33 + nl] = v.w;
    }
    if (t < 32)
      idxf[nbase + t] = (float)(unsigned)(packed[nbase + t] & 0xFFFFFFFFull);
  }
  __syncthreads();

  const int w = t & 31, cg = t >> 5;
  const size_t base = (size_t)(blk >> 5) * 262144 + (size_t)(blk & 31) * 32 + w;
  float local = 0.f;
#pragma unroll
  for (int cc = 0; cc < 32; ++cc) {
    const int c = cg * 32 + cc;
    const float q  = zqT[c * 33 + w];
    const float zv = z[base + (size_t)c * 1024];
    out[base + (size_t)c * 1024] = q;
    const float dd = q - zv;
    local = fmaf(dd, dd, local);
  }
  float v = local;
#pragma unroll
  for (int m = 1; m < 64; m <<= 1) v += __shfl_xor(v, m, 64);
  if ((t & 63) == 0) part[t >> 6] = v;
  __syncthreads();
  if (t == 0) atomicAdd(ssum, part[0] + part[1] + part[2] + part[3]);
}

// ---- K4: finalize scalars ----
__global__ void k_final(const float* __restrict__ ssum, float* __restrict__ scal) {
  const float m = *ssum * INV_M;
  scal[0] = 1.25f * m;   // loss
  scal[1] = 0.25f * m;   // commitment_loss
  scal[2] = m;           // codebook_loss
}

extern "C" void kernel_launch(void* const* d_in, const int* in_sizes, int n_in,
                              void* d_out, int out_size, void* d_ws, size_t ws_size,
                              hipStream_t stream) {
  const float* z    = (const float*)d_in[0];
  const float* emb  = (const float*)d_in[1];
  const float* proj = (const float*)d_in[2];

  float* out  = (float*)d_out;
  float* scal = out + 4194304;
  float* idxf = out + 4194307;

  // ws (~22 MB): cb | norms | packed | znorm | zf | ef | rowminG | rowThr | rowcnt | slots | ssum
  float* cb    = (float*)d_ws;                          // 8 MB
  float* norms = cb + 2097152;                          // 32 KB
  unsigned long long* packed =
      (unsigned long long*)(norms + 8192);              // 128 KB
  float* znorm = (float*)(packed + 16384);              // 64 KB
  u16* zf = (u16*)(znorm + 16384);                      // 8.4 MB (fragment-order)
  u16* ef = zf + 4194304;                               // 4.2 MB (fragment-order)
  u32* rowminG = (u32*)(ef + 2097152);                  // 64 KB
  float* rowThr = (float*)(rowminG + 16384);            // 64 KB
  u32* rowcnt = (u32*)(rowThr + 16384);                 // 64 KB
  u16* slots = (u16*)(rowcnt + 16384);                  // 1 MB
  float* ssum = (float*)(slots + 16384 * 32);           // 4 B

  hipMemsetAsync(rowminG, 0xFF, 16384 * sizeof(u32), stream);
  hipMemsetAsync(rowcnt, 0, 16384 * sizeof(u32), stream);
  hipMemsetAsync(packed, 0xFF, 16384 * sizeof(unsigned long long), stream);
  hipMemsetAsync(ssum, 0, sizeof(float), stream);

  k_codebook<<<dim3(128, 4), 256, 0, stream>>>(emb, proj, cb, ef);
  k_norms   <<<32, 256, 0, stream>>>(cb, norms);
  k_prep_z  <<<512, 256, 0, stream>>>(z, zf, znorm);
  k_scan<false><<<2048, 256, 0, stream>>>(zf, ef, norms, znorm,
                                          rowminG, rowThr, rowcnt, slots);
  k_thresh  <<<64, 256, 0, stream>>>(rowminG, rowThr);
  k_scan<true> <<<2048, 256, 0, stream>>>(zf, ef, norms, znorm,
                                          rowminG, rowThr, rowcnt, slots);
  k_rescore <<<512, 256, 0, stream>>>(z, cb, norms, znorm, rowcnt, slots, packed);
  k_output  <<<512, 256, 0, stream>>>(z, cb, packed, out, idxf, ssum);
  k_final   <<<1, 1, 0, stream>>>(ssum, scal);

  (void)in_sizes; (void)n_in; (void)out_size; (void)ws_size;
}

// Round 8
// 461.825 us; speedup vs baseline: 1.2373x; 1.2373x over previous
//
#include <hip/hip_runtime.h>
#include <cfloat>

// VQ forward, MI355X. z[16,256,32,32] f32, emb[8192,256] f32, proj[256,256] f32.
// N = 16384 rows, K = 8192 codes, D = 256.
// d_out (floats): out[4194304] | loss | commitment | codebook_loss | idx_as_float[16384]
//
// R16: SINGLE-PASS scan with running threshold (eliminates scanA+k_thresh).
//  Per (kt,cq) quad: MFMA scores -> row-min reduce -> atomicMin into rowminG
//  (device-scope, returns old; coherent across XCDs) -> thr = min(old, own)+DLT
//  -> emit sc <= thr into slots (128/row; count via rowcnt). Correctness proof:
//  for true winner k*, any posted sc >= s-err >= s*-err and sc* <= s*+err, so
//  sc* <= g + 2err <= g + DLT (DLT=1e-3 > 2*3.2e-4) -> k* and all exact ties
//  always emitted, under any race/staleness (staleness only loosens thr).
//  k_rescore: exact fp32 rescore of slots (quantized fold, packed (monof<<32|k)
//  min -> first-index ties); if a row's count > 128 (never expected; ~35 mean,
//  ~6 sigma margin), full-8192 exact fallback keeps it correct.
//
// R15 post-mortem baked in: __launch_bounds__(256,2) ONLY. (256,4) capped the
//  unified reg file at 128; acc took 64 -> A/B buffers spilled per-iteration ->
//  650 MB scratch traffic/dispatch (VGPR=64, WRITE 202 MB counters). Live set
//  ~130 regs; never constrain below (256,2).
//  Scan geometry = R15's verified quad structure: wave (rowhalf,colhalf) =
//  32 rows x 128 cols; per kt two col-quads; acc[2][4]; A/B reg double-buffer
//  distance-1; fragment-ordered zf/ef (1KB coalesced fragment loads); plain
//  __syncthreads per kt bounds wave drift for L1 reuse of duplicate granules.

constexpr int Dd = 256;
constexpr float INV_M = 1.0f / 4194304.0f;
constexpr float DLT = 1e-3f;
constexpr int SLOTS = 128;

typedef unsigned short u16;
typedef unsigned int u32;
typedef __attribute__((ext_vector_type(8))) short short8;   // 8 bf16
typedef __attribute__((ext_vector_type(4))) float f32x4;

__device__ __forceinline__ unsigned monof(float f) {
  unsigned u = __float_as_uint(f);
  return (u & 0x80000000u) ? ~u : (u | 0x80000000u);
}
__device__ __forceinline__ float unmonof(unsigned p) {
  unsigned u = (p & 0x80000000u) ? (p & 0x7FFFFFFFu) : ~p;
  return __uint_as_float(u);
}
__device__ __forceinline__ u16 f2bf(float x) {   // RNE float->bf16 bits
  unsigned u = __float_as_uint(x);
  u += 0x7FFFu + ((u >> 16) & 1u);
  return (u16)(u >> 16);
}

// ---- K1: codebook = emb @ proj^T -> cb[k][d] fp32 + ef bf16 fragment-order ----
__global__ __launch_bounds__(256)
void k_codebook(const float* __restrict__ emb, const float* __restrict__ proj,
                float* __restrict__ cb, u16* __restrict__ ef) {
  __shared__ float et[64 * 65];
  __shared__ float pt[64 * 65];
  __shared__ __align__(16) u16 tileT[64 * 72];
  const int t = threadIdx.x;
  const int tx = t & 15, ty = t >> 4;
  const int kb = blockIdx.x * 64;
  const int db = blockIdx.y * 64;
  float acc[4][4];
#pragma unroll
  for (int u = 0; u < 4; ++u)
#pragma unroll
    for (int v = 0; v < 4; ++v) acc[u][v] = 0.f;

  const int jm = t & 15;
  const int q  = t >> 4;

  for (int jc = 0; jc < Dd; jc += 64) {
    __syncthreads();
#pragma unroll
    for (int i = 0; i < 4; ++i) {
      const int row = q + i * 16;
      const float4 e4 = *(const float4*)(emb  + (size_t)(kb + row) * Dd + jc + jm * 4);
      const float4 p4 = *(const float4*)(proj + (size_t)(db + row) * Dd + jc + jm * 4);
      et[(jm*4 + 0) * 65 + row] = e4.x;
      et[(jm*4 + 1) * 65 + row] = e4.y;
      et[(jm*4 + 2) * 65 + row] = e4.z;
      et[(jm*4 + 3) * 65 + row] = e4.w;
      pt[(jm*4 + 0) * 65 + row] = p4.x;
      pt[(jm*4 + 1) * 65 + row] = p4.y;
      pt[(jm*4 + 2) * 65 + row] = p4.z;
      pt[(jm*4 + 3) * 65 + row] = p4.w;
    }
    __syncthreads();
#pragma unroll 16
    for (int j = 0; j < 64; ++j) {
      float a[4], b[4];
#pragma unroll
      for (int u = 0; u < 4; ++u) a[u] = et[j*65 + ty*4 + u];
#pragma unroll
      for (int v = 0; v < 4; ++v) b[v] = pt[j*65 + tx*4 + v];
#pragma unroll
      for (int u = 0; u < 4; ++u)
#pragma unroll
        for (int v = 0; v < 4; ++v) acc[u][v] = fmaf(a[u], b[v], acc[u][v]);
    }
  }
  // fp32 cb (linear) + bf16 tile to LDS for fragment-order shuffle
#pragma unroll
  for (int u = 0; u < 4; ++u) {
    const int k = kb + ty*4 + u;
#pragma unroll
    for (int v = 0; v < 4; ++v) {
      const int d = db + tx*4 + v;
      const float val = acc[u][v];
      cb[(size_t)k * Dd + d] = val;
      tileT[(ty*4 + u) * 72 + tx*4 + v] = f2bf(val);
    }
  }
  __syncthreads();
  // emit 512 fragment granules (16 B each), coalesced
  uint4* ef16 = (uint4*)ef;
#pragma unroll
  for (int w2 = 0; w2 < 2; ++w2) {
    const int uu = w2 * 256 + t;
    const int k16g = uu >> 7;            // 0..3 (16-k group within tile)
    const int d32g = (uu >> 6) & 1;      // 0..1 (32-d group within tile)
    const int ln   = uu & 63;            // fragment lane
    const int klo  = k16g * 16 + (ln & 15);
    const int dlo  = d32g * 32 + (ln >> 4) * 8;
    ef16[((kb >> 4) + k16g) * 512 + ((db >> 5) + d32g) * 64 + ln] =
        *(const uint4*)&tileT[klo * 72 + dlo];
  }
}

// ---- K1b: per-code norms (ascending-d fmaf chain) ----
__global__ __launch_bounds__(256)
void k_norms(const float* __restrict__ cb, float* __restrict__ norms) {
  const int k = blockIdx.x * 256 + threadIdx.x;
  const float* row = cb + (size_t)k * Dd;
  float s = 0.f;
  for (int d = 0; d < Dd; d += 4) {
    const float4 v = *(const float4*)(row + d);
    s = fmaf(v.x, v.x, s);
    s = fmaf(v.y, v.y, s);
    s = fmaf(v.z, v.z, s);
    s = fmaf(v.w, v.w, s);
  }
  norms[k] = s;
}

// ---- K1c: transpose z -> zf bf16 fragment-order + znorm ----
__global__ __launch_bounds__(256)
void k_prep_z(const float* __restrict__ z, u16* __restrict__ zf,
              float* __restrict__ znorm) {
  __shared__ float tile[256 * 33];
  const int t = threadIdx.x;
  const int blk = blockIdx.x;            // b*32 + h
  const int w = t & 31, rg = t >> 5;
  const size_t zbase = (size_t)(blk >> 5) * 262144 + (size_t)(blk & 31) * 32 + w;
#pragma unroll 8
  for (int i = 0; i < 32; ++i) {
    const int d = rg * 32 + i;
    tile[d * 33 + w] = z[zbase + (size_t)d * 1024];
  }
  __syncthreads();
  if (t < 32) {
    float s = 0.f;
    for (int d = 0; d < Dd; ++d) {
      const float v = tile[d * 33 + t];
      s = fmaf(v, v, s);
    }
    znorm[blk * 32 + t] = s;
  }
  // fragment-order write: granule U = ((n>>4)*8 + d32)*64 + qd*16 + (n&15)
  const int ml16 = t & 15;
  const int seg  = (t >> 4) & 7;         // d32 group
  const int hi   = t >> 7;               // n16 group within block (0/1)
  const int nl   = hi * 16 + ml16;       // row 0..31 within block
  uint4* zf16 = (uint4*)zf;
  const int ubase = ((blk * 2 + hi) * 8 + seg) * 64 + ml16;
#pragma unroll
  for (int j = 0; j < 4; ++j) {          // qd octet
    u16 hb[8];
#pragma unroll
    for (int e = 0; e < 8; ++e)
      hb[e] = f2bf(tile[(seg * 32 + j * 8 + e) * 33 + nl]);
    zf16[ubase + j * 16] = *(const uint4*)hb;
  }
}

// ---- K2: single-pass MFMA scan with running-threshold emission ----
// Block 64 rows x 1024 cols; wave (rowhalf,colhalf) = 32 rows x 128 cols.
__global__ __launch_bounds__(256, 2)
void k_scan(const u16* __restrict__ zf, const u16* __restrict__ ef,
            const float* __restrict__ norms, const float* __restrict__ znorm,
            u32* __restrict__ rowminG, u32* __restrict__ rowcnt,
            u16* __restrict__ slots) {
  const int t    = threadIdx.x;
  const int lane = t & 63;
  const int ml   = lane & 15;
  const int qd   = lane >> 4;
  const int wvu  = __builtin_amdgcn_readfirstlane(t >> 6);
  const int rowhalf = wvu & 1;           // 0/1 -> 32 rows
  const int colhalf = wvu >> 1;          // 0/1 -> 128 cols (of kt's 256)
  const int bid  = blockIdx.x;
  const int kb   = (bid & 7) * 1024;     // colgroup -> XCD-local ef reuse
  const int nb   = (bid >> 3) * 64;

  const uint4* zf16 = (const uint4*)zf;
  const uint4* ef16 = (const uint4*)ef;
  // A granule (rt,d32): za + rt*512 + d32*64
  const uint4* za = zf16 + (size_t)((nb >> 4) + rowhalf * 2) * 512 + lane;
  // B granule (kt,cq,ct,d32): eb + ((kt*16)+(cq*4)+ct)*512 + d32*64
  const uint4* eb = ef16 + (size_t)((kb >> 4) + colhalf * 8) * 512 + lane;

  // per-thread rows: n = nb + rowhalf*32 + rt*16 + qd*4 + r
  float zn[2][4];
#pragma unroll
  for (int rt = 0; rt < 2; ++rt) {
    const int nr = nb + rowhalf * 32 + rt * 16 + qd * 4;
    const f32x4 z4 = *(const f32x4*)(znorm + nr);
#pragma unroll
    for (int r = 0; r < 4; ++r) zn[rt][r] = z4[r];
  }

#pragma unroll 1
  for (int kt = 0; kt < 4; ++kt) {
    const size_t ekt = (size_t)kt * 16 * 512;
#pragma unroll
    for (int cq = 0; cq < 2; ++cq) {
      const uint4* ecq = eb + ekt + (size_t)(cq * 4) * 512;

      f32x4 acc[2][4];
#pragma unroll
      for (int rt = 0; rt < 2; ++rt)
#pragma unroll
        for (int ct = 0; ct < 4; ++ct) acc[rt][ct] = (f32x4)0.f;

      short8 Aa0[2], Aa1[2], Bb0[4], Bb1[4];
      // prologue: d32 = 0 into buf0
#pragma unroll
      for (int rt = 0; rt < 2; ++rt) Aa0[rt] = *(const short8*)(za + rt * 512);
#pragma unroll
      for (int ct = 0; ct < 4; ++ct) Bb0[ct] = *(const short8*)(ecq + ct * 512);

#pragma unroll
      for (int d32 = 0; d32 < 8; ++d32) {
        if (d32 < 7) {                       // distance-1 prefetch of d32+1
          const int off = (d32 + 1) * 64;
          if (d32 & 1) {                     // current buf1 -> fill buf0
#pragma unroll
            for (int rt = 0; rt < 2; ++rt)
              Aa0[rt] = *(const short8*)(za + rt * 512 + off);
#pragma unroll
            for (int ct = 0; ct < 4; ++ct)
              Bb0[ct] = *(const short8*)(ecq + ct * 512 + off);
          } else {                           // current buf0 -> fill buf1
#pragma unroll
            for (int rt = 0; rt < 2; ++rt)
              Aa1[rt] = *(const short8*)(za + rt * 512 + off);
#pragma unroll
            for (int ct = 0; ct < 4; ++ct)
              Bb1[ct] = *(const short8*)(ecq + ct * 512 + off);
          }
        }
        if (d32 & 1) {
#pragma unroll
          for (int ct = 0; ct < 4; ++ct)
#pragma unroll
            for (int rt = 0; rt < 2; ++rt)
              acc[rt][ct] = __builtin_amdgcn_mfma_f32_16x16x32_bf16(
                  Aa1[rt], Bb1[ct], acc[rt][ct], 0, 0, 0);
        } else {
#pragma unroll
          for (int ct = 0; ct < 4; ++ct)
#pragma unroll
            for (int rt = 0; rt < 2; ++rt)
              acc[rt][ct] = __builtin_amdgcn_mfma_f32_16x16x32_bf16(
                  Aa0[rt], Bb0[ct], acc[rt][ct], 0, 0, 0);
        }
      }

      // ---- scores in place: acc[rt][ct][r] = (zn + nk) - 2*acc  (quantized fold)
#pragma unroll
      for (int ct = 0; ct < 4; ++ct) {
        const int k0 = kb + kt * 256 + colhalf * 128 + cq * 64 + ct * 16 + ml;
        const float nkv = norms[k0];
#pragma unroll
        for (int rt = 0; rt < 2; ++rt)
#pragma unroll
          for (int r = 0; r < 4; ++r)
            acc[rt][ct][r] = (zn[rt][r] + nkv) - 2.0f * acc[rt][ct][r];
      }

      // ---- per-row quad min (over ct, then over 16 ml lanes) ----
      float m2[2][4];
#pragma unroll
      for (int rt = 0; rt < 2; ++rt)
#pragma unroll
        for (int r = 0; r < 4; ++r) {
          float m = fminf(fminf(acc[rt][0][r], acc[rt][1][r]),
                          fminf(acc[rt][2][r], acc[rt][3][r]));
#pragma unroll
          for (int s = 1; s < 16; s <<= 1) m = fminf(m, __shfl_xor(m, s, 64));
          m2[rt][r] = m;
        }

      // ---- atomicMin exchange (lane ml==j handles row j), broadcast ----
      unsigned myg = 0xFFFFFFFFu;
      if (ml < 8) {
        const int rt = ml >> 2, r = ml & 3;
        const int n = nb + rowhalf * 32 + rt * 16 + qd * 4 + r;
        const unsigned pk = monof(m2[rt][r]);
        const unsigned old = atomicMin(&rowminG[n], pk);
        myg = min(old, pk);
      }
      float thrv[2][4];
#pragma unroll
      for (int rt = 0; rt < 2; ++rt)
#pragma unroll
        for (int r = 0; r < 4; ++r) {
          const unsigned gg = __shfl(myg, (lane & 48) + rt * 4 + r, 64);
          thrv[rt][r] = unmonof(gg) + DLT;
        }

      // ---- emit candidates: sc <= freshest-global-min + DLT ----
#pragma unroll
      for (int ct = 0; ct < 4; ++ct) {
        const int k = kb + kt * 256 + colhalf * 128 + cq * 64 + ct * 16 + ml;
#pragma unroll
        for (int rt = 0; rt < 2; ++rt)
#pragma unroll
          for (int r = 0; r < 4; ++r) {
            if (acc[rt][ct][r] <= thrv[rt][r]) {
              const int n = nb + rowhalf * 32 + rt * 16 + qd * 4 + r;
              const u32 pos = atomicAdd(&rowcnt[n], 1u);
              if (pos < (u32)SLOTS) slots[n * SLOTS + pos] = (u16)k;
            }
          }
      }
    }
    __syncthreads();   // bound wave drift: partner waves' duplicate A/B reads hit L1
  }
}

// ---- K2c: exact rescore of slot candidates (full-scan fallback on overflow) ----
// Block per (b,h): 32 rows; LDS z-tile [32][261] fp32; wave per 8 rows.
__global__ __launch_bounds__(256)
void k_rescore(const float* __restrict__ z, const float* __restrict__ cb,
               const float* __restrict__ norms, const float* __restrict__ znorm,
               const u32* __restrict__ rowcnt, const u16* __restrict__ slots,
               unsigned long long* __restrict__ packed) {
  __shared__ float ztl[32 * 261];
  const int t = threadIdx.x;
  const int blk = blockIdx.x;          // b*32 + h
  const int w = t & 31, dg = t >> 5;
  const size_t zbase = (size_t)(blk >> 5) * 262144 + (size_t)(blk & 31) * 32;
#pragma unroll 8
  for (int i = 0; i < 32; ++i) {
    const int d = dg * 32 + i;
    ztl[w * 261 + d] = z[zbase + (size_t)d * 1024 + w];
  }
  __syncthreads();

  const int lane = t & 63;
  const int wv = t >> 6;               // 4 waves
  // 4 waves x 8 rows each
#pragma unroll 1
  for (int i = 0; i < 8; ++i) {
    const int rl = wv * 8 + i;
    const int n = blk * 32 + rl;
    const u32 cnt = rowcnt[n];
    const float znr = znorm[n];
    const float* zp = ztl + rl * 261 + lane * 4;
    unsigned long long best = 0xFFFFFFFFFFFFFFFFull;
    if (cnt <= (u32)SLOTS) {
      for (u32 c = 0; c < cnt; ++c) {
        const int k = (int)slots[n * SLOTS + c] & 8191;   // guard
        const float4 c4 = *(const float4*)(cb + (size_t)k * Dd + lane * 4);
        float p = 0.f;
        p = fmaf(zp[0], c4.x, p);
        p = fmaf(zp[1], c4.y, p);
        p = fmaf(zp[2], c4.z, p);
        p = fmaf(zp[3], c4.w, p);
#pragma unroll
        for (int s = 1; s < 64; s <<= 1) p += __shfl_xor(p, s, 64);
        const float sc = (znr + norms[k]) - 2.0f * p;   // quantized fold
        const unsigned long long pk =
            ((unsigned long long)monof(sc) << 32) | (unsigned)k;
        if (pk < best) best = pk;                        // ties -> min k
      }
    } else {
      // overflow fallback (never expected): exact scan of all 8192 codes
      for (int k = 0; k < 8192; ++k) {
        const float4 c4 = *(const float4*)(cb + (size_t)k * Dd + lane * 4);
        float p = 0.f;
        p = fmaf(zp[0], c4.x, p);
        p = fmaf(zp[1], c4.y, p);
        p = fmaf(zp[2], c4.z, p);
        p = fmaf(zp[3], c4.w, p);
#pragma unroll
        for (int s = 1; s < 64; s <<= 1) p += __shfl_xor(p, s, 64);
        const float sc = (znr + norms[k]) - 2.0f * p;
        const unsigned long long pk =
            ((unsigned long long)monof(sc) << 32) | (unsigned)k;
        if (pk < best) best = pk;
      }
    }
    if (lane == 0 && cnt > 0) packed[n] = best;
  }
}

// ---- K3: gather codes, write out (NCHW), idx floats, reduce SSE ----
__global__ __launch_bounds__(256)
void k_output(const float* __restrict__ z, const float* __restrict__ cb,
              const unsigned long long* __restrict__ packed,
              float* __restrict__ out, float* __restrict__ idxf,
              float* __restrict__ ssum) {
  __shared__ float zqT[256 * 33];
  __shared__ float part[4];
  const int t = threadIdx.x;
  const int blk = blockIdx.x;       // = b*32 + h
  const int nbase = blk * 32;

  {
    const int nl = t >> 3, m = t & 7;
    // guard the GATHER address only (&8191): if upstream ever leaves the
    // sentinel, we return wrong values (checker catches) instead of faulting.
    const int idx = (int)(packed[nbase + nl] & 0xFFFFFFFFull) & 8191;
    const float* row = cb + (size_t)idx * Dd;
#pragma unroll
    for (int i = 0; i < 8; ++i) {
      const int d0 = m * 4 + i * 32;
      const float4 v = *(const float4*)(row + d0);
      zqT[(d0 + 0) * 33 + nl] = v.x;
      zqT[(d0 + 1) * 33 + nl] = v.y;
      zqT[(d0 + 2) * 33 + nl] = v.z;
      zqT[(d0 + 3) * 33 + nl] = v.w;
    }
    if (t < 32)
      idxf[nbase + t] = (float)(unsigned)(packed[nbase + t] & 0xFFFFFFFFull);
  }
  __syncthreads();

  const int w = t & 31, cg = t >> 5;
  const size_t base = (size_t)(blk >> 5) * 262144 + (size_t)(blk & 31) * 32 + w;
  float local = 0.f;
#pragma unroll
  for (int cc = 0; cc < 32; ++cc) {
    const int c = cg * 32 + cc;
    const float q  = zqT[c * 33 + w];
    const float zv = z[base + (size_t)c * 1024];
    out[base + (size_t)c * 1024] = q;
    const float dd = q - zv;
    local = fmaf(dd, dd, local);
  }
  float v = local;
#pragma unroll
  for (int m = 1; m < 64; m <<= 1) v += __shfl_xor(v, m, 64);
  if ((t & 63) == 0) part[t >> 6] = v;
  __syncthreads();
  if (t == 0) atomicAdd(ssum, part[0] + part[1] + part[2] + part[3]);
}

// ---- K4: finalize scalars ----
__global__ void k_final(const float* __restrict__ ssum, float* __restrict__ scal) {
  const float m = *ssum * INV_M;
  scal[0] = 1.25f * m;   // loss
  scal[1] = 0.25f * m;   // commitment_loss
  scal[2] = m;           // codebook_loss
}

extern "C" void kernel_launch(void* const* d_in, const int* in_sizes, int n_in,
                              void* d_out, int out_size, void* d_ws, size_t ws_size,
                              hipStream_t stream) {
  const float* z    = (const float*)d_in[0];
  const float* emb  = (const float*)d_in[1];
  const float* proj = (const float*)d_in[2];

  float* out  = (float*)d_out;
  float* scal = out + 4194304;
  float* idxf = out + 4194307;

  // ws (~24.6 MB): cb | norms | packed | znorm | zf | ef | rowminG | rowcnt | slots | ssum
  float* cb    = (float*)d_ws;                          // 8 MB
  float* norms = cb + 2097152;                          // 32 KB
  unsigned long long* packed =
      (unsigned long long*)(norms + 8192);              // 128 KB
  float* znorm = (float*)(packed + 16384);              // 64 KB
  u16* zf = (u16*)(znorm + 16384);                      // 8.4 MB (fragment-order)
  u16* ef = zf + 4194304;                               // 4.2 MB (fragment-order)
  u32* rowminG = (u32*)(ef + 2097152);                  // 64 KB
  u32* rowcnt = rowminG + 16384;                        // 64 KB
  u16* slots = (u16*)(rowcnt + 16384);                  // 4 MB (128/row)
  float* ssum = (float*)(slots + (size_t)16384 * SLOTS);// 4 B

  hipMemsetAsync(rowminG, 0xFF, 16384 * sizeof(u32), stream);
  hipMemsetAsync(rowcnt, 0, 16384 * sizeof(u32), stream);
  hipMemsetAsync(packed, 0xFF, 16384 * sizeof(unsigned long long), stream);
  hipMemsetAsync(ssum, 0, sizeof(float), stream);

  k_codebook<<<dim3(128, 4), 256, 0, stream>>>(emb, proj, cb, ef);
  k_norms   <<<32, 256, 0, stream>>>(cb, norms);
  k_prep_z  <<<512, 256, 0, stream>>>(z, zf, znorm);
  k_scan    <<<2048, 256, 0, stream>>>(zf, ef, norms, znorm,
                                       rowminG, rowcnt, slots);
  k_rescore <<<512, 256, 0, stream>>>(z, cb, norms, znorm, rowcnt, slots, packed);
  k_output  <<<512, 256, 0, stream>>>(z, cb, packed, out, idxf, ssum);
  k_final   <<<1, 1, 0, stream>>>(ssum, scal);

  (void)in_sizes; (void)n_in; (void)out_size; (void)ws_size;
}

// Round 9
// 393.321 us; speedup vs baseline: 1.4528x; 1.1742x over previous
//
#include <hip/hip_runtime.h>
#include <cfloat>

// VQ forward, MI355X. z[16,256,32,32] f32, emb[8192,256] f32, proj[256,256] f32.
// N = 16384 rows, K = 8192 codes, D = 256.
// d_out (floats): out[4194304] | loss | commitment | codebook_loss | idx_as_float[16384]
//
// R17: single-pass scan (R16, verified) + score-carrying slots + filtered rescore.
//  R16 post-mortem: scan 212 us but rescore blew up (non-scan 126->249 us):
//  running-threshold emission produces ~40-120 cands/row (16 wave-streams), and
//  each cost a full exact wave-dot; overflow rows hit the 8192 fallback on one
//  wave. Fix: emission stores u32 = quant19(sc - zn)<<13 | k  (sc-zn in +-0.07,
//  Sterbenz-exact; fixed point 2^-21 res). k_rescore filters by the FINAL global
//  min (rowminG) + DLT before exact rescoring: filter-set superset of exact ties
//  (sc* <= g + 2err <= g + DLT), subset of emitted (running thr >= final thr).
//  Exact work back to ~4-6/row. DLT 1e-3 -> 8e-4 (still 25% above deterministic
//  2err = 6.4e-4) trims emissions; SLOTS=128 overflow >= 9 sigma away; full-scan
//  fallback retained as correctness net.
//  Scan structure unchanged from R16 (passing): quad geometry, reg double-buffer,
//  sync atomicMin exchange, __launch_bounds__(256,2) (R15: NEVER below 2).

constexpr int Dd = 256;
constexpr float INV_M = 1.0f / 4194304.0f;
constexpr float DLT = 8e-4f;
constexpr int SLOTS = 128;

typedef unsigned short u16;
typedef unsigned int u32;
typedef __attribute__((ext_vector_type(8))) short short8;   // 8 bf16
typedef __attribute__((ext_vector_type(4))) float f32x4;

__device__ __forceinline__ unsigned monof(float f) {
  unsigned u = __float_as_uint(f);
  return (u & 0x80000000u) ? ~u : (u | 0x80000000u);
}
__device__ __forceinline__ float unmonof(unsigned p) {
  unsigned u = (p & 0x80000000u) ? (p & 0x7FFFFFFFu) : ~p;
  return __uint_as_float(u);
}
__device__ __forceinline__ u16 f2bf(float x) {   // RNE float->bf16 bits
  unsigned u = __float_as_uint(x);
  u += 0x7FFFu + ((u >> 16) & 1u);
  return (u16)(u >> 16);
}

// ---- K1: codebook = emb @ proj^T -> cb[k][d] fp32 + ef bf16 fragment-order ----
__global__ __launch_bounds__(256)
void k_codebook(const float* __restrict__ emb, const float* __restrict__ proj,
                float* __restrict__ cb, u16* __restrict__ ef) {
  __shared__ float et[64 * 65];
  __shared__ float pt[64 * 65];
  __shared__ __align__(16) u16 tileT[64 * 72];
  const int t = threadIdx.x;
  const int tx = t & 15, ty = t >> 4;
  const int kb = blockIdx.x * 64;
  const int db = blockIdx.y * 64;
  float acc[4][4];
#pragma unroll
  for (int u = 0; u < 4; ++u)
#pragma unroll
    for (int v = 0; v < 4; ++v) acc[u][v] = 0.f;

  const int jm = t & 15;
  const int q  = t >> 4;

  for (int jc = 0; jc < Dd; jc += 64) {
    __syncthreads();
#pragma unroll
    for (int i = 0; i < 4; ++i) {
      const int row = q + i * 16;
      const float4 e4 = *(const float4*)(emb  + (size_t)(kb + row) * Dd + jc + jm * 4);
      const float4 p4 = *(const float4*)(proj + (size_t)(db + row) * Dd + jc + jm * 4);
      et[(jm*4 + 0) * 65 + row] = e4.x;
      et[(jm*4 + 1) * 65 + row] = e4.y;
      et[(jm*4 + 2) * 65 + row] = e4.z;
      et[(jm*4 + 3) * 65 + row] = e4.w;
      pt[(jm*4 + 0) * 65 + row] = p4.x;
      pt[(jm*4 + 1) * 65 + row] = p4.y;
      pt[(jm*4 + 2) * 65 + row] = p4.z;
      pt[(jm*4 + 3) * 65 + row] = p4.w;
    }
    __syncthreads();
#pragma unroll 16
    for (int j = 0; j < 64; ++j) {
      float a[4], b[4];
#pragma unroll
      for (int u = 0; u < 4; ++u) a[u] = et[j*65 + ty*4 + u];
#pragma unroll
      for (int v = 0; v < 4; ++v) b[v] = pt[j*65 + tx*4 + v];
#pragma unroll
      for (int u = 0; u < 4; ++u)
#pragma unroll
        for (int v = 0; v < 4; ++v) acc[u][v] = fmaf(a[u], b[v], acc[u][v]);
    }
  }
  // fp32 cb (linear) + bf16 tile to LDS for fragment-order shuffle
#pragma unroll
  for (int u = 0; u < 4; ++u) {
    const int k = kb + ty*4 + u;
#pragma unroll
    for (int v = 0; v < 4; ++v) {
      const int d = db + tx*4 + v;
      const float val = acc[u][v];
      cb[(size_t)k * Dd + d] = val;
      tileT[(ty*4 + u) * 72 + tx*4 + v] = f2bf(val);
    }
  }
  __syncthreads();
  // emit 512 fragment granules (16 B each), coalesced
  uint4* ef16 = (uint4*)ef;
#pragma unroll
  for (int w2 = 0; w2 < 2; ++w2) {
    const int uu = w2 * 256 + t;
    const int k16g = uu >> 7;            // 0..3 (16-k group within tile)
    const int d32g = (uu >> 6) & 1;      // 0..1 (32-d group within tile)
    const int ln   = uu & 63;            // fragment lane
    const int klo  = k16g * 16 + (ln & 15);
    const int dlo  = d32g * 32 + (ln >> 4) * 8;
    ef16[((kb >> 4) + k16g) * 512 + ((db >> 5) + d32g) * 64 + ln] =
        *(const uint4*)&tileT[klo * 72 + dlo];
  }
}

// ---- K1b: per-code norms (ascending-d fmaf chain) ----
__global__ __launch_bounds__(256)
void k_norms(const float* __restrict__ cb, float* __restrict__ norms) {
  const int k = blockIdx.x * 256 + threadIdx.x;
  const float* row = cb + (size_t)k * Dd;
  float s = 0.f;
  for (int d = 0; d < Dd; d += 4) {
    const float4 v = *(const float4*)(row + d);
    s = fmaf(v.x, v.x, s);
    s = fmaf(v.y, v.y, s);
    s = fmaf(v.z, v.z, s);
    s = fmaf(v.w, v.w, s);
  }
  norms[k] = s;
}

// ---- K1c: transpose z -> zf bf16 fragment-order + znorm ----
__global__ __launch_bounds__(256)
void k_prep_z(const float* __restrict__ z, u16* __restrict__ zf,
              float* __restrict__ znorm) {
  __shared__ float tile[256 * 33];
  const int t = threadIdx.x;
  const int blk = blockIdx.x;            // b*32 + h
  const int w = t & 31, rg = t >> 5;
  const size_t zbase = (size_t)(blk >> 5) * 262144 + (size_t)(blk & 31) * 32 + w;
#pragma unroll 8
  for (int i = 0; i < 32; ++i) {
    const int d = rg * 32 + i;
    tile[d * 33 + w] = z[zbase + (size_t)d * 1024];
  }
  __syncthreads();
  if (t < 32) {
    float s = 0.f;
    for (int d = 0; d < Dd; ++d) {
      const float v = tile[d * 33 + t];
      s = fmaf(v, v, s);
    }
    znorm[blk * 32 + t] = s;
  }
  // fragment-order write: granule U = ((n>>4)*8 + d32)*64 + qd*16 + (n&15)
  const int ml16 = t & 15;
  const int seg  = (t >> 4) & 7;         // d32 group
  const int hi   = t >> 7;               // n16 group within block (0/1)
  const int nl   = hi * 16 + ml16;       // row 0..31 within block
  uint4* zf16 = (uint4*)zf;
  const int ubase = ((blk * 2 + hi) * 8 + seg) * 64 + ml16;
#pragma unroll
  for (int j = 0; j < 4; ++j) {          // qd octet
    u16 hb[8];
#pragma unroll
    for (int e = 0; e < 8; ++e)
      hb[e] = f2bf(tile[(seg * 32 + j * 8 + e) * 33 + nl]);
    zf16[ubase + j * 16] = *(const uint4*)hb;
  }
}

// ---- K2: single-pass MFMA scan with running-threshold emission ----
// Block 64 rows x 1024 cols; wave (rowhalf,colhalf) = 32 rows x 128 cols.
__global__ __launch_bounds__(256, 2)
void k_scan(const u16* __restrict__ zf, const u16* __restrict__ ef,
            const float* __restrict__ norms, const float* __restrict__ znorm,
            u32* __restrict__ rowminG, u32* __restrict__ rowcnt,
            u32* __restrict__ slots) {
  const int t    = threadIdx.x;
  const int lane = t & 63;
  const int ml   = lane & 15;
  const int qd   = lane >> 4;
  const int wvu  = __builtin_amdgcn_readfirstlane(t >> 6);
  const int rowhalf = wvu & 1;           // 0/1 -> 32 rows
  const int colhalf = wvu >> 1;          // 0/1 -> 128 cols (of kt's 256)
  const int bid  = blockIdx.x;
  const int kb   = (bid & 7) * 1024;     // colgroup -> XCD-local ef reuse
  const int nb   = (bid >> 3) * 64;

  const uint4* zf16 = (const uint4*)zf;
  const uint4* ef16 = (const uint4*)ef;
  // A granule (rt,d32): za + rt*512 + d32*64
  const uint4* za = zf16 + (size_t)((nb >> 4) + rowhalf * 2) * 512 + lane;
  // B granule (kt,cq,ct,d32): eb + ((kt*16)+(cq*4)+ct)*512 + d32*64
  const uint4* eb = ef16 + (size_t)((kb >> 4) + colhalf * 8) * 512 + lane;

  // per-thread rows: n = nb + rowhalf*32 + rt*16 + qd*4 + r
  float zn[2][4];
#pragma unroll
  for (int rt = 0; rt < 2; ++rt) {
    const int nr = nb + rowhalf * 32 + rt * 16 + qd * 4;
    const f32x4 z4 = *(const f32x4*)(znorm + nr);
#pragma unroll
    for (int r = 0; r < 4; ++r) zn[rt][r] = z4[r];
  }

#pragma unroll 1
  for (int kt = 0; kt < 4; ++kt) {
    const size_t ekt = (size_t)kt * 16 * 512;
#pragma unroll
    for (int cq = 0; cq < 2; ++cq) {
      const uint4* ecq = eb + ekt + (size_t)(cq * 4) * 512;

      f32x4 acc[2][4];
#pragma unroll
      for (int rt = 0; rt < 2; ++rt)
#pragma unroll
        for (int ct = 0; ct < 4; ++ct) acc[rt][ct] = (f32x4)0.f;

      short8 Aa0[2], Aa1[2], Bb0[4], Bb1[4];
      // prologue: d32 = 0 into buf0
#pragma unroll
      for (int rt = 0; rt < 2; ++rt) Aa0[rt] = *(const short8*)(za + rt * 512);
#pragma unroll
      for (int ct = 0; ct < 4; ++ct) Bb0[ct] = *(const short8*)(ecq + ct * 512);

#pragma unroll
      for (int d32 = 0; d32 < 8; ++d32) {
        if (d32 < 7) {                       // distance-1 prefetch of d32+1
          const int off = (d32 + 1) * 64;
          if (d32 & 1) {                     // current buf1 -> fill buf0
#pragma unroll
            for (int rt = 0; rt < 2; ++rt)
              Aa0[rt] = *(const short8*)(za + rt * 512 + off);
#pragma unroll
            for (int ct = 0; ct < 4; ++ct)
              Bb0[ct] = *(const short8*)(ecq + ct * 512 + off);
          } else {                           // current buf0 -> fill buf1
#pragma unroll
            for (int rt = 0; rt < 2; ++rt)
              Aa1[rt] = *(const short8*)(za + rt * 512 + off);
#pragma unroll
            for (int ct = 0; ct < 4; ++ct)
              Bb1[ct] = *(const short8*)(ecq + ct * 512 + off);
          }
        }
        if (d32 & 1) {
#pragma unroll
          for (int ct = 0; ct < 4; ++ct)
#pragma unroll
            for (int rt = 0; rt < 2; ++rt)
              acc[rt][ct] = __builtin_amdgcn_mfma_f32_16x16x32_bf16(
                  Aa1[rt], Bb1[ct], acc[rt][ct], 0, 0, 0);
        } else {
#pragma unroll
          for (int ct = 0; ct < 4; ++ct)
#pragma unroll
            for (int rt = 0; rt < 2; ++rt)
              acc[rt][ct] = __builtin_amdgcn_mfma_f32_16x16x32_bf16(
                  Aa0[rt], Bb0[ct], acc[rt][ct], 0, 0, 0);
        }
      }

      // ---- scores in place: acc[rt][ct][r] = (zn + nk) - 2*acc  (quantized fold)
#pragma unroll
      for (int ct = 0; ct < 4; ++ct) {
        const int k0 = kb + kt * 256 + colhalf * 128 + cq * 64 + ct * 16 + ml;
        const float nkv = norms[k0];
#pragma unroll
        for (int rt = 0; rt < 2; ++rt)
#pragma unroll
          for (int r = 0; r < 4; ++r)
            acc[rt][ct][r] = (zn[rt][r] + nkv) - 2.0f * acc[rt][ct][r];
      }

      // ---- per-row quad min (over ct, then over 16 ml lanes) ----
      float m2[2][4];
#pragma unroll
      for (int rt = 0; rt < 2; ++rt)
#pragma unroll
        for (int r = 0; r < 4; ++r) {
          float m = fminf(fminf(acc[rt][0][r], acc[rt][1][r]),
                          fminf(acc[rt][2][r], acc[rt][3][r]));
#pragma unroll
          for (int s = 1; s < 16; s <<= 1) m = fminf(m, __shfl_xor(m, s, 64));
          m2[rt][r] = m;
        }

      // ---- atomicMin exchange (lane ml==j handles row j), broadcast ----
      unsigned myg = 0xFFFFFFFFu;
      if (ml < 8) {
        const int rt = ml >> 2, r = ml & 3;
        const int n = nb + rowhalf * 32 + rt * 16 + qd * 4 + r;
        const unsigned pk = monof(m2[rt][r]);
        const unsigned old = atomicMin(&rowminG[n], pk);
        myg = min(old, pk);
      }
      float thrv[2][4];
#pragma unroll
      for (int rt = 0; rt < 2; ++rt)
#pragma unroll
        for (int r = 0; r < 4; ++r) {
          const unsigned gg = __shfl(myg, (lane & 48) + rt * 4 + r, 64);
          thrv[rt][r] = unmonof(gg) + DLT;
        }

      // ---- emit candidates: sc <= freshest-global-min + DLT ----
      // slot payload: quant19(sc - zn) << 13 | k  (Sterbenz-exact sc-zn, 2^-21 res)
#pragma unroll
      for (int ct = 0; ct < 4; ++ct) {
        const int k = kb + kt * 256 + colhalf * 128 + cq * 64 + ct * 16 + ml;
#pragma unroll
        for (int rt = 0; rt < 2; ++rt)
#pragma unroll
          for (int r = 0; r < 4; ++r) {
            if (acc[rt][ct][r] <= thrv[rt][r]) {
              const int n = nb + rowhalf * 32 + rt * 16 + qd * 4 + r;
              const u32 pos = atomicAdd(&rowcnt[n], 1u);
              if (pos < (u32)SLOTS) {
                const float e = acc[rt][ct][r] - zn[rt][r];
                int q = __float2int_rn(e * 2097152.0f) + 262144;
                q = q < 0 ? 0 : (q > 524287 ? 524287 : q);
                slots[n * SLOTS + pos] = ((u32)q << 13) | (u32)k;
              }
            }
          }
      }
    }
    __syncthreads();   // bound wave drift: partner waves' duplicate A/B reads hit L1
  }
}

// ---- K2c: filtered exact rescore (full-scan fallback on overflow) ----
// Block per (b,h): 32 rows; LDS z-tile [32][261] fp32; wave per 8 rows.
__global__ __launch_bounds__(256)
void k_rescore(const float* __restrict__ z, const float* __restrict__ cb,
               const float* __restrict__ norms, const float* __restrict__ znorm,
               const u32* __restrict__ rowminG, const u32* __restrict__ rowcnt,
               const u32* __restrict__ slots,
               unsigned long long* __restrict__ packed) {
  __shared__ float ztl[32 * 261];
  const int t = threadIdx.x;
  const int blk = blockIdx.x;          // b*32 + h
  const int w = t & 31, dg = t >> 5;
  const size_t zbase = (size_t)(blk >> 5) * 262144 + (size_t)(blk & 31) * 32;
#pragma unroll 8
  for (int i = 0; i < 32; ++i) {
    const int d = dg * 32 + i;
    ztl[w * 261 + d] = z[zbase + (size_t)d * 1024 + w];
  }
  __syncthreads();

  const int lane = t & 63;
  const int wv = t >> 6;               // 4 waves
  // 4 waves x 8 rows each
#pragma unroll 1
  for (int i = 0; i < 8; ++i) {
    const int rl = wv * 8 + i;
    const int n = blk * 32 + rl;
    const u32 cnt = rowcnt[n];
    const float znr = znorm[n];
    const float* zp = ztl + rl * 261 + lane * 4;
    // final-threshold filter in encoded domain (+68 LSB covers all rounding)
    const float g = unmonof(rowminG[n]);
    const int qThr = __float2int_rn((g + DLT - znr) * 2097152.0f) + 262144 + 68;
    unsigned long long best = 0xFFFFFFFFFFFFFFFFull;
    if (cnt <= (u32)SLOTS) {
      for (u32 c = 0; c < cnt; ++c) {
        const u32 v = slots[n * SLOTS + c];      // wave-uniform addr -> broadcast
        if ((int)(v >> 13) > qThr) continue;     // uniform branch
        const int k = (int)(v & 8191u);
        const float4 c4 = *(const float4*)(cb + (size_t)k * Dd + lane * 4);
        float p = 0.f;
        p = fmaf(zp[0], c4.x, p);
        p = fmaf(zp[1], c4.y, p);
        p = fmaf(zp[2], c4.z, p);
        p = fmaf(zp[3], c4.w, p);
#pragma unroll
        for (int s = 1; s < 64; s <<= 1) p += __shfl_xor(p, s, 64);
        const float sc = (znr + norms[k]) - 2.0f * p;   // quantized fold
        const unsigned long long pk =
            ((unsigned long long)monof(sc) << 32) | (unsigned)k;
        if (pk < best) best = pk;                        // ties -> min k
      }
    } else {
      // overflow fallback (>=9 sigma away): exact scan of all 8192 codes
      for (int k = 0; k < 8192; ++k) {
        const float4 c4 = *(const float4*)(cb + (size_t)k * Dd + lane * 4);
        float p = 0.f;
        p = fmaf(zp[0], c4.x, p);
        p = fmaf(zp[1], c4.y, p);
        p = fmaf(zp[2], c4.z, p);
        p = fmaf(zp[3], c4.w, p);
#pragma unroll
        for (int s = 1; s < 64; s <<= 1) p += __shfl_xor(p, s, 64);
        const float sc = (znr + norms[k]) - 2.0f * p;
        const unsigned long long pk =
            ((unsigned long long)monof(sc) << 32) | (unsigned)k;
        if (pk < best) best = pk;
      }
    }
    if (lane == 0 && cnt > 0) packed[n] = best;
  }
}

// ---- K3: gather codes, write out (NCHW), idx floats, reduce SSE ----
__global__ __launch_bounds__(256)
void k_output(const float* __restrict__ z, const float* __restrict__ cb,
              const unsigned long long* __restrict__ packed,
              float* __restrict__ out, float* __restrict__ idxf,
              float* __restrict__ ssum) {
  __shared__ float zqT[256 * 33];
  __shared__ float part[4];
  const int t = threadIdx.x;
  const int blk = blockIdx.x;       // = b*32 + h
  const int nbase = blk * 32;

  {
    const int nl = t >> 3, m = t & 7;
    // guard the GATHER address only (&8191): if upstream ever leaves the
    // sentinel, we return wrong values (checker catches) instead of faulting.
    const int idx = (int)(packed[nbase + nl] & 0xFFFFFFFFull) & 8191;
    const float* row = cb + (size_t)idx * Dd;
#pragma unroll
    for (int i = 0; i < 8; ++i) {
      const int d0 = m * 4 + i * 32;
      const float4 v = *(const float4*)(row + d0);
      zqT[(d0 + 0) * 33 + nl] = v.x;
      zqT[(d0 + 1) * 33 + nl] = v.y;
      zqT[(d0 + 2) * 33 + nl] = v.z;
      zqT[(d0 + 3) * 33 + nl] = v.w;
    }
    if (t < 32)
      idxf[nbase + t] = (float)(unsigned)(packed[nbase + t] & 0xFFFFFFFFull);
  }
  __syncthreads();

  const int w = t & 31, cg = t >> 5;
  const size_t base = (size_t)(blk >> 5) * 262144 + (size_t)(blk & 31) * 32 + w;
  float local = 0.f;
#pragma unroll
  for (int cc = 0; cc < 32; ++cc) {
    const int c = cg * 32 + cc;
    const float q  = zqT[c * 33 + w];
    const float zv = z[base + (size_t)c * 1024];
    out[base + (size_t)c * 1024] = q;
    const float dd = q - zv;
    local = fmaf(dd, dd, local);
  }
  float v = local;
#pragma unroll
  for (int m = 1; m < 64; m <<= 1) v += __shfl_xor(v, m, 64);
  if ((t & 63) == 0) part[t >> 6] = v;
  __syncthreads();
  if (t == 0) atomicAdd(ssum, part[0] + part[1] + part[2] + part[3]);
}

// ---- K4: finalize scalars ----
__global__ void k_final(const float* __restrict__ ssum, float* __restrict__ scal) {
  const float m = *ssum * INV_M;
  scal[0] = 1.25f * m;   // loss
  scal[1] = 0.25f * m;   // commitment_loss
  scal[2] = m;           // codebook_loss
}

extern "C" void kernel_launch(void* const* d_in, const int* in_sizes, int n_in,
                              void* d_out, int out_size, void* d_ws, size_t ws_size,
                              hipStream_t stream) {
  const float* z    = (const float*)d_in[0];
  const float* emb  = (const float*)d_in[1];
  const float* proj = (const float*)d_in[2];

  float* out  = (float*)d_out;
  float* scal = out + 4194304;
  float* idxf = out + 4194307;

  // ws (~28.9 MB): cb | norms | packed | znorm | zf | ef | rowminG | rowcnt | slots(u32) | ssum
  float* cb    = (float*)d_ws;                          // 8 MB
  float* norms = cb + 2097152;                          // 32 KB
  unsigned long long* packed =
      (unsigned long long*)(norms + 8192);              // 128 KB
  float* znorm = (float*)(packed + 16384);              // 64 KB
  u16* zf = (u16*)(znorm + 16384);                      // 8.4 MB (fragment-order)
  u16* ef = zf + 4194304;                               // 4.2 MB (fragment-order)
  u32* rowminG = (u32*)(ef + 2097152);                  // 64 KB
  u32* rowcnt = rowminG + 16384;                        // 64 KB
  u32* slots = rowcnt + 16384;                          // 8 MB (128 u32/row)
  float* ssum = (float*)(slots + (size_t)16384 * SLOTS);// 4 B

  hipMemsetAsync(rowminG, 0xFF, 16384 * sizeof(u32), stream);
  hipMemsetAsync(rowcnt, 0, 16384 * sizeof(u32), stream);
  hipMemsetAsync(packed, 0xFF, 16384 * sizeof(unsigned long long), stream);
  hipMemsetAsync(ssum, 0, sizeof(float), stream);

  k_codebook<<<dim3(128, 4), 256, 0, stream>>>(emb, proj, cb, ef);
  k_norms   <<<32, 256, 0, stream>>>(cb, norms);
  k_prep_z  <<<512, 256, 0, stream>>>(z, zf, znorm);
  k_scan    <<<2048, 256, 0, stream>>>(zf, ef, norms, znorm,
                                       rowminG, rowcnt, slots);
  k_rescore <<<512, 256, 0, stream>>>(z, cb, norms, znorm,
                                      rowminG, rowcnt, slots, packed);
  k_output  <<<512, 256, 0, stream>>>(z, cb, packed, out, idxf, ssum);
  k_final   <<<1, 1, 0, stream>>>(ssum, scal);

  (void)in_sizes; (void)n_in; (void)out_size; (void)ws_size;
}

// Round 10
// 387.754 us; speedup vs baseline: 1.4736x; 1.0144x over previous
//
#include <hip/hip_runtime.h>
#include <cfloat>

// VQ forward, MI355X. z[16,256,32,32] f32, emb[8192,256] f32, proj[256,256] f32.
// N = 16384 rows, K = 8192 codes, D = 256.
// d_out (floats): out[4194304] | loss | commitment | codebook_loss | idx_as_float[16384]
//
// R17 (393 us, PASS): single-pass scan, running-threshold emission, score-carrying
//  slots (quant19(sc-zn)<<13|k), final-threshold-filtered exact rescore.
// R18: scan latency fixes, dataflow bit-identical to R17:
//  (1) A fragments hoisted to registers (16 granules = 64 VGPR, loaded once).
//      R17 re-fetched A every quad (za independent of kt/cq): 512 KB/block of
//      redundant L1/L2 traffic + a load dependency in every d32 step.
//  (2) Seamless B stream: global step s = kt*16+cq*8+d32 has parity d32&1
//      (cq*8, kt*16 even) -> same two B buffers alternate across all 64 steps;
//      at d32=7 the prefetch targets the NEXT quad's d32=0 (static per unrolled
//      arm) so the fold/atomicMin/emit tail runs with next loads in flight --
//      no cold restart at quad boundaries (was 8 full drains/wave).
//  (3) k_codebook: et/pt stride 65->68 floats (16B-aligned, 2-way bank = free)
//      -> float4 LDS reads (8 ds_read_b32 -> 2 ds_read_b128 per j). Same values,
//      same fmaf order -> cb bit-identical.
//  Reg budget: A 64 + B 2x4x4=32 + acc 32 + zn/thr/misc ~35 => ~165 (no spill
//  expected; falsifier VGPR>=200 / WRITE_SIZE jump). __launch_bounds__(256,2)
//  (R15 lesson: never cap below the ~170 live set).

constexpr int Dd = 256;
constexpr float INV_M = 1.0f / 4194304.0f;
constexpr float DLT = 8e-4f;
constexpr int SLOTS = 128;

typedef unsigned short u16;
typedef unsigned int u32;
typedef __attribute__((ext_vector_type(8))) short short8;   // 8 bf16
typedef __attribute__((ext_vector_type(4))) float f32x4;

__device__ __forceinline__ unsigned monof(float f) {
  unsigned u = __float_as_uint(f);
  return (u & 0x80000000u) ? ~u : (u | 0x80000000u);
}
__device__ __forceinline__ float unmonof(unsigned p) {
  unsigned u = (p & 0x80000000u) ? (p & 0x7FFFFFFFu) : ~p;
  return __uint_as_float(u);
}
__device__ __forceinline__ u16 f2bf(float x) {   // RNE float->bf16 bits
  unsigned u = __float_as_uint(x);
  u += 0x7FFFu + ((u >> 16) & 1u);
  return (u16)(u >> 16);
}

// ---- K1: codebook = emb @ proj^T -> cb[k][d] fp32 + ef bf16 fragment-order ----
__global__ __launch_bounds__(256)
void k_codebook(const float* __restrict__ emb, const float* __restrict__ proj,
                float* __restrict__ cb, u16* __restrict__ ef) {
  __shared__ __align__(16) float et[64 * 68];
  __shared__ __align__(16) float pt[64 * 68];
  __shared__ __align__(16) u16 tileT[64 * 72];
  const int t = threadIdx.x;
  const int tx = t & 15, ty = t >> 4;
  const int kb = blockIdx.x * 64;
  const int db = blockIdx.y * 64;
  float acc[4][4];
#pragma unroll
  for (int u = 0; u < 4; ++u)
#pragma unroll
    for (int v = 0; v < 4; ++v) acc[u][v] = 0.f;

  const int jm = t & 15;
  const int q  = t >> 4;

  for (int jc = 0; jc < Dd; jc += 64) {
    __syncthreads();
#pragma unroll
    for (int i = 0; i < 4; ++i) {
      const int row = q + i * 16;
      const float4 e4 = *(const float4*)(emb  + (size_t)(kb + row) * Dd + jc + jm * 4);
      const float4 p4 = *(const float4*)(proj + (size_t)(db + row) * Dd + jc + jm * 4);
      et[(jm*4 + 0) * 68 + row] = e4.x;
      et[(jm*4 + 1) * 68 + row] = e4.y;
      et[(jm*4 + 2) * 68 + row] = e4.z;
      et[(jm*4 + 3) * 68 + row] = e4.w;
      pt[(jm*4 + 0) * 68 + row] = p4.x;
      pt[(jm*4 + 1) * 68 + row] = p4.y;
      pt[(jm*4 + 2) * 68 + row] = p4.z;
      pt[(jm*4 + 3) * 68 + row] = p4.w;
    }
    __syncthreads();
#pragma unroll 16
    for (int j = 0; j < 64; ++j) {
      const float4 a4 = *(const float4*)(et + j * 68 + ty * 4);
      const float4 b4 = *(const float4*)(pt + j * 68 + tx * 4);
      const float a[4] = {a4.x, a4.y, a4.z, a4.w};
      const float b[4] = {b4.x, b4.y, b4.z, b4.w};
#pragma unroll
      for (int u = 0; u < 4; ++u)
#pragma unroll
        for (int v = 0; v < 4; ++v) acc[u][v] = fmaf(a[u], b[v], acc[u][v]);
    }
  }
  // fp32 cb (linear) + bf16 tile to LDS for fragment-order shuffle
#pragma unroll
  for (int u = 0; u < 4; ++u) {
    const int k = kb + ty*4 + u;
#pragma unroll
    for (int v = 0; v < 4; ++v) {
      const int d = db + tx*4 + v;
      const float val = acc[u][v];
      cb[(size_t)k * Dd + d] = val;
      tileT[(ty*4 + u) * 72 + tx*4 + v] = f2bf(val);
    }
  }
  __syncthreads();
  // emit 512 fragment granules (16 B each), coalesced
  uint4* ef16 = (uint4*)ef;
#pragma unroll
  for (int w2 = 0; w2 < 2; ++w2) {
    const int uu = w2 * 256 + t;
    const int k16g = uu >> 7;            // 0..3 (16-k group within tile)
    const int d32g = (uu >> 6) & 1;      // 0..1 (32-d group within tile)
    const int ln   = uu & 63;            // fragment lane
    const int klo  = k16g * 16 + (ln & 15);
    const int dlo  = d32g * 32 + (ln >> 4) * 8;
    ef16[((kb >> 4) + k16g) * 512 + ((db >> 5) + d32g) * 64 + ln] =
        *(const uint4*)&tileT[klo * 72 + dlo];
  }
}

// ---- K1b: per-code norms (ascending-d fmaf chain) ----
__global__ __launch_bounds__(256)
void k_norms(const float* __restrict__ cb, float* __restrict__ norms) {
  const int k = blockIdx.x * 256 + threadIdx.x;
  const float* row = cb + (size_t)k * Dd;
  float s = 0.f;
  for (int d = 0; d < Dd; d += 4) {
    const float4 v = *(const float4*)(row + d);
    s = fmaf(v.x, v.x, s);
    s = fmaf(v.y, v.y, s);
    s = fmaf(v.z, v.z, s);
    s = fmaf(v.w, v.w, s);
  }
  norms[k] = s;
}

// ---- K1c: transpose z -> zf bf16 fragment-order + znorm ----
__global__ __launch_bounds__(256)
void k_prep_z(const float* __restrict__ z, u16* __restrict__ zf,
              float* __restrict__ znorm) {
  __shared__ float tile[256 * 33];
  const int t = threadIdx.x;
  const int blk = blockIdx.x;            // b*32 + h
  const int w = t & 31, rg = t >> 5;
  const size_t zbase = (size_t)(blk >> 5) * 262144 + (size_t)(blk & 31) * 32 + w;
#pragma unroll 8
  for (int i = 0; i < 32; ++i) {
    const int d = rg * 32 + i;
    tile[d * 33 + w] = z[zbase + (size_t)d * 1024];
  }
  __syncthreads();
  if (t < 32) {
    float s = 0.f;
    for (int d = 0; d < Dd; ++d) {
      const float v = tile[d * 33 + t];
      s = fmaf(v, v, s);
    }
    znorm[blk * 32 + t] = s;
  }
  // fragment-order write: granule U = ((n>>4)*8 + d32)*64 + qd*16 + (n&15)
  const int ml16 = t & 15;
  const int seg  = (t >> 4) & 7;         // d32 group
  const int hi   = t >> 7;               // n16 group within block (0/1)
  const int nl   = hi * 16 + ml16;       // row 0..31 within block
  uint4* zf16 = (uint4*)zf;
  const int ubase = ((blk * 2 + hi) * 8 + seg) * 64 + ml16;
#pragma unroll
  for (int j = 0; j < 4; ++j) {          // qd octet
    u16 hb[8];
#pragma unroll
    for (int e = 0; e < 8; ++e)
      hb[e] = f2bf(tile[(seg * 32 + j * 8 + e) * 33 + nl]);
    zf16[ubase + j * 16] = *(const uint4*)hb;
  }
}

// ---- K2: single-pass MFMA scan, A-resident + seamless B stream ----
// Block 64 rows x 1024 cols; wave (rowhalf,colhalf) = 32 rows x 128 cols.
__global__ __launch_bounds__(256, 2)
void k_scan(const u16* __restrict__ zf, const u16* __restrict__ ef,
            const float* __restrict__ norms, const float* __restrict__ znorm,
            u32* __restrict__ rowminG, u32* __restrict__ rowcnt,
            u32* __restrict__ slots) {
  const int t    = threadIdx.x;
  const int lane = t & 63;
  const int ml   = lane & 15;
  const int qd   = lane >> 4;
  const int wvu  = __builtin_amdgcn_readfirstlane(t >> 6);
  const int rowhalf = wvu & 1;           // 0/1 -> 32 rows
  const int colhalf = wvu >> 1;          // 0/1 -> 128 cols (of kt's 256)
  const int bid  = blockIdx.x;
  const int kb   = (bid & 7) * 1024;     // colgroup -> XCD-local ef reuse
  const int nb   = (bid >> 3) * 64;

  const uint4* zf16 = (const uint4*)zf;
  const uint4* ef16 = (const uint4*)ef;
  // B granule (kt,cq,ct,d32): eb + ((kt*16)+(cq*4)+ct)*512 + d32*64
  const uint4* eb = ef16 + (size_t)((kb >> 4) + colhalf * 8) * 512 + lane;

  // ---- A resident in VGPR: A[rt][d32], 16 granules = 64 VGPR, loaded once ----
  short8 A[2][8];
  {
    const uint4* za = zf16 + (size_t)((nb >> 4) + rowhalf * 2) * 512 + lane;
#pragma unroll
    for (int rt = 0; rt < 2; ++rt)
#pragma unroll
      for (int d32 = 0; d32 < 8; ++d32)
        A[rt][d32] = *(const short8*)(za + rt * 512 + d32 * 64);
  }

  // per-thread rows: n = nb + rowhalf*32 + rt*16 + qd*4 + r
  float zn[2][4];
#pragma unroll
  for (int rt = 0; rt < 2; ++rt) {
    const int nr = nb + rowhalf * 32 + rt * 16 + qd * 4;
    const f32x4 z4 = *(const f32x4*)(znorm + nr);
#pragma unroll
    for (int r = 0; r < 4; ++r) zn[rt][r] = z4[r];
  }

  // ---- seamless B stream: two buffers alternate by d32 parity across quads ----
  short8 Bb0[4], Bb1[4];
#pragma unroll
  for (int ct = 0; ct < 4; ++ct) Bb0[ct] = *(const short8*)(eb + ct * 512);

#pragma unroll 1
  for (int kt = 0; kt < 4; ++kt) {
    const size_t ekt = (size_t)kt * 16 * 512;
#pragma unroll
    for (int cq = 0; cq < 2; ++cq) {
      const uint4* ecq = eb + ekt + (size_t)(cq * 4) * 512;

      f32x4 acc[2][4];
#pragma unroll
      for (int rt = 0; rt < 2; ++rt)
#pragma unroll
        for (int ct = 0; ct < 4; ++ct) acc[rt][ct] = (f32x4)0.f;

#pragma unroll
      for (int d32 = 0; d32 < 8; ++d32) {
        // prefetch the NEXT stream step (possibly next quad / next kt):
        const bool last = (kt == 3) && (cq == 1) && (d32 == 7);
        if (!last) {
          const uint4* pnext;
          if (d32 < 7) {
            pnext = ecq + (d32 + 1) * 64;                  // same quad
          } else if (cq == 0) {
            pnext = eb + ekt + (size_t)4 * 512;            // quad cq=1, d32=0
          } else {
            pnext = eb + ekt + (size_t)16 * 512;           // next kt, cq=0, d32=0
          }
          if (d32 & 1) {
#pragma unroll
            for (int ct = 0; ct < 4; ++ct)
              Bb0[ct] = *(const short8*)(pnext + ct * 512);
          } else {
#pragma unroll
            for (int ct = 0; ct < 4; ++ct)
              Bb1[ct] = *(const short8*)(pnext + ct * 512);
          }
        }
        if (d32 & 1) {
#pragma unroll
          for (int ct = 0; ct < 4; ++ct)
#pragma unroll
            for (int rt = 0; rt < 2; ++rt)
              acc[rt][ct] = __builtin_amdgcn_mfma_f32_16x16x32_bf16(
                  A[rt][d32], Bb1[ct], acc[rt][ct], 0, 0, 0);
        } else {
#pragma unroll
          for (int ct = 0; ct < 4; ++ct)
#pragma unroll
            for (int rt = 0; rt < 2; ++rt)
              acc[rt][ct] = __builtin_amdgcn_mfma_f32_16x16x32_bf16(
                  A[rt][d32], Bb0[ct], acc[rt][ct], 0, 0, 0);
        }
      }

      // ---- scores in place: acc = (zn + nk) - 2*acc  (quantized fold) ----
#pragma unroll
      for (int ct = 0; ct < 4; ++ct) {
        const int k0 = kb + kt * 256 + colhalf * 128 + cq * 64 + ct * 16 + ml;
        const float nkv = norms[k0];
#pragma unroll
        for (int rt = 0; rt < 2; ++rt)
#pragma unroll
          for (int r = 0; r < 4; ++r)
            acc[rt][ct][r] = (zn[rt][r] + nkv) - 2.0f * acc[rt][ct][r];
      }

      // ---- per-row quad min (over ct, then over 16 ml lanes) ----
      float m2[2][4];
#pragma unroll
      for (int rt = 0; rt < 2; ++rt)
#pragma unroll
        for (int r = 0; r < 4; ++r) {
          float m = fminf(fminf(acc[rt][0][r], acc[rt][1][r]),
                          fminf(acc[rt][2][r], acc[rt][3][r]));
#pragma unroll
          for (int s = 1; s < 16; s <<= 1) m = fminf(m, __shfl_xor(m, s, 64));
          m2[rt][r] = m;
        }

      // ---- atomicMin exchange (lane ml==j handles row j), broadcast ----
      unsigned myg = 0xFFFFFFFFu;
      if (ml < 8) {
        const int rt = ml >> 2, r = ml & 3;
        const int n = nb + rowhalf * 32 + rt * 16 + qd * 4 + r;
        const unsigned pk = monof(m2[rt][r]);
        const unsigned old = atomicMin(&rowminG[n], pk);
        myg = min(old, pk);
      }
      float thrv[2][4];
#pragma unroll
      for (int rt = 0; rt < 2; ++rt)
#pragma unroll
        for (int r = 0; r < 4; ++r) {
          const unsigned gg = __shfl(myg, (lane & 48) + rt * 4 + r, 64);
          thrv[rt][r] = unmonof(gg) + DLT;
        }

      // ---- emit candidates: sc <= freshest-global-min + DLT ----
      // slot payload: quant19(sc - zn) << 13 | k  (Sterbenz-exact sc-zn, 2^-21 res)
#pragma unroll
      for (int ct = 0; ct < 4; ++ct) {
        const int k = kb + kt * 256 + colhalf * 128 + cq * 64 + ct * 16 + ml;
#pragma unroll
        for (int rt = 0; rt < 2; ++rt)
#pragma unroll
          for (int r = 0; r < 4; ++r) {
            if (acc[rt][ct][r] <= thrv[rt][r]) {
              const int n = nb + rowhalf * 32 + rt * 16 + qd * 4 + r;
              const u32 pos = atomicAdd(&rowcnt[n], 1u);
              if (pos < (u32)SLOTS) {
                const float e = acc[rt][ct][r] - zn[rt][r];
                int q = __float2int_rn(e * 2097152.0f) + 262144;
                q = q < 0 ? 0 : (q > 524287 ? 524287 : q);
                slots[n * SLOTS + pos] = ((u32)q << 13) | (u32)k;
              }
            }
          }
      }
    }
    __syncthreads();   // bound wave drift: partner waves' duplicate B reads hit L1
  }
}

// ---- K2c: filtered exact rescore (full-scan fallback on overflow) ----
// Block per (b,h): 32 rows; LDS z-tile [32][261] fp32; wave per 8 rows.
__global__ __launch_bounds__(256)
void k_rescore(const float* __restrict__ z, const float* __restrict__ cb,
               const float* __restrict__ norms, const float* __restrict__ znorm,
               const u32* __restrict__ rowminG, const u32* __restrict__ rowcnt,
               const u32* __restrict__ slots,
               unsigned long long* __restrict__ packed) {
  __shared__ float ztl[32 * 261];
  const int t = threadIdx.x;
  const int blk = blockIdx.x;          // b*32 + h
  const int w = t & 31, dg = t >> 5;
  const size_t zbase = (size_t)(blk >> 5) * 262144 + (size_t)(blk & 31) * 32;
#pragma unroll 8
  for (int i = 0; i < 32; ++i) {
    const int d = dg * 32 + i;
    ztl[w * 261 + d] = z[zbase + (size_t)d * 1024 + w];
  }
  __syncthreads();

  const int lane = t & 63;
  const int wv = t >> 6;               // 4 waves
  // 4 waves x 8 rows each
#pragma unroll 1
  for (int i = 0; i < 8; ++i) {
    const int rl = wv * 8 + i;
    const int n = blk * 32 + rl;
    const u32 cnt = rowcnt[n];
    const float znr = znorm[n];
    const float* zp = ztl + rl * 261 + lane * 4;
    // final-threshold filter in encoded domain (+68 LSB covers all rounding)
    const float g = unmonof(rowminG[n]);
    const int qThr = __float2int_rn((g + DLT - znr) * 2097152.0f) + 262144 + 68;
    unsigned long long best = 0xFFFFFFFFFFFFFFFFull;
    if (cnt <= (u32)SLOTS) {
      for (u32 c = 0; c < cnt; ++c) {
        const u32 v = slots[n * SLOTS + c];      // wave-uniform addr -> broadcast
        if ((int)(v >> 13) > qThr) continue;     // uniform branch
        const int k = (int)(v & 8191u);
        const float4 c4 = *(const float4*)(cb + (size_t)k * Dd + lane * 4);
        float p = 0.f;
        p = fmaf(zp[0], c4.x, p);
        p = fmaf(zp[1], c4.y, p);
        p = fmaf(zp[2], c4.z, p);
        p = fmaf(zp[3], c4.w, p);
#pragma unroll
        for (int s = 1; s < 64; s <<= 1) p += __shfl_xor(p, s, 64);
        const float sc = (znr + norms[k]) - 2.0f * p;   // quantized fold
        const unsigned long long pk =
            ((unsigned long long)monof(sc) << 32) | (unsigned)k;
        if (pk < best) best = pk;                        // ties -> min k
      }
    } else {
      // overflow fallback (>=9 sigma away): exact scan of all 8192 codes
      for (int k = 0; k < 8192; ++k) {
        const float4 c4 = *(const float4*)(cb + (size_t)k * Dd + lane * 4);
        float p = 0.f;
        p = fmaf(zp[0], c4.x, p);
        p = fmaf(zp[1], c4.y, p);
        p = fmaf(zp[2], c4.z, p);
        p = fmaf(zp[3], c4.w, p);
#pragma unroll
        for (int s = 1; s < 64; s <<= 1) p += __shfl_xor(p, s, 64);
        const float sc = (znr + norms[k]) - 2.0f * p;
        const unsigned long long pk =
            ((unsigned long long)monof(sc) << 32) | (unsigned)k;
        if (pk < best) best = pk;
      }
    }
    if (lane == 0 && cnt > 0) packed[n] = best;
  }
}

// ---- K3: gather codes, write out (NCHW), idx floats, reduce SSE ----
__global__ __launch_bounds__(256)
void k_output(const float* __restrict__ z, const float* __restrict__ cb,
              const unsigned long long* __restrict__ packed,
              float* __restrict__ out, float* __restrict__ idxf,
              float* __restrict__ ssum) {
  __shared__ float zqT[256 * 33];
  __shared__ float part[4];
  const int t = threadIdx.x;
  const int blk = blockIdx.x;       // = b*32 + h
  const int nbase = blk * 32;

  {
    const int nl = t >> 3, m = t & 7;
    // guard the GATHER address only (&8191): if upstream ever leaves the
    // sentinel, we return wrong values (checker catches) instead of faulting.
    const int idx = (int)(packed[nbase + nl] & 0xFFFFFFFFull) & 8191;
    const float* row = cb + (size_t)idx * Dd;
#pragma unroll
    for (int i = 0; i < 8; ++i) {
      const int d0 = m * 4 + i * 32;
      const float4 v = *(const float4*)(row + d0);
      zqT[(d0 + 0) * 33 + nl] = v.x;
      zqT[(d0 + 1) * 33 + nl] = v.y;
      zqT[(d0 + 2) * 33 + nl] = v.z;
      zqT[(d0 + 3) * 33 + nl] = v.w;
    }
    if (t < 32)
      idxf[nbase + t] = (float)(unsigned)(packed[nbase + t] & 0xFFFFFFFFull);
  }
  __syncthreads();

  const int w = t & 31, cg = t >> 5;
  const size_t base = (size_t)(blk >> 5) * 262144 + (size_t)(blk & 31) * 32 + w;
  float local = 0.f;
#pragma unroll
  for (int cc = 0; cc < 32; ++cc) {
    const int c = cg * 32 + cc;
    const float q  = zqT[c * 33 + w];
    const float zv = z[base + (size_t)c * 1024];
    out[base + (size_t)c * 1024] = q;
    const float dd = q - zv;
    local = fmaf(dd, dd, local);
  }
  float v = local;
#pragma unroll
  for (int m = 1; m < 64; m <<= 1) v += __shfl_xor(v, m, 64);
  if ((t & 63) == 0) part[t >> 6] = v;
  __syncthreads();
  if (t == 0) atomicAdd(ssum, part[0] + part[1] + part[2] + part[3]);
}

// ---- K4: finalize scalars ----
__global__ void k_final(const float* __restrict__ ssum, float* __restrict__ scal) {
  const float m = *ssum * INV_M;
  scal[0] = 1.25f * m;   // loss
  scal[1] = 0.25f * m;   // commitment_loss
  scal[2] = m;           // codebook_loss
}

extern "C" void kernel_launch(void* const* d_in, const int* in_sizes, int n_in,
                              void* d_out, int out_size, void* d_ws, size_t ws_size,
                              hipStream_t stream) {
  const float* z    = (const float*)d_in[0];
  const float* emb  = (const float*)d_in[1];
  const float* proj = (const float*)d_in[2];

  float* out  = (float*)d_out;
  float* scal = out + 4194304;
  float* idxf = out + 4194307;

  // ws (~28.9 MB): cb | norms | packed | znorm | zf | ef | rowminG | rowcnt | slots(u32) | ssum
  float* cb    = (float*)d_ws;                          // 8 MB
  float* norms = cb + 2097152;                          // 32 KB
  unsigned long long* packed =
      (unsigned long long*)(norms + 8192);              // 128 KB
  float* znorm = (float*)(packed + 16384);              // 64 KB
  u16* zf = (u16*)(znorm + 16384);                      // 8.4 MB (fragment-order)
  u16* ef = zf + 4194304;                               // 4.2 MB (fragment-order)
  u32* rowminG = (u32*)(ef + 2097152);                  // 64 KB
  u32* rowcnt = rowminG + 16384;                        // 64 KB
  u32* slots = rowcnt + 16384;                          // 8 MB (128 u32/row)
  float* ssum = (float*)(slots + (size_t)16384 * SLOTS);// 4 B

  hipMemsetAsync(rowminG, 0xFF, 16384 * sizeof(u32), stream);
  hipMemsetAsync(rowcnt, 0, 16384 * sizeof(u32), stream);
  hipMemsetAsync(packed, 0xFF, 16384 * sizeof(unsigned long long), stream);
  hipMemsetAsync(ssum, 0, sizeof(float), stream);

  k_codebook<<<dim3(128, 4), 256, 0, stream>>>(emb, proj, cb, ef);
  k_norms   <<<32, 256, 0, stream>>>(cb, norms);
  k_prep_z  <<<512, 256, 0, stream>>>(z, zf, znorm);
  k_scan    <<<2048, 256, 0, stream>>>(zf, ef, norms, znorm,
                                       rowminG, rowcnt, slots);
  k_rescore <<<512, 256, 0, stream>>>(z, cb, norms, znorm,
                                      rowminG, rowcnt, slots, packed);
  k_output  <<<512, 256, 0, stream>>>(z, cb, packed, out, idxf, ssum);
  k_final   <<<1, 1, 0, stream>>>(ssum, scal);

  (void)in_sizes; (void)n_in; (void)out_size; (void)ws_size;
}